// Round 7
// baseline (1574.822 us; speedup 1.0000x reference)
//
#include <hip/hip_runtime.h>
#include <math.h>

#define FEATS 32
#define NNODE 33
#define HID   1024
#define INGRU 68640        // 33*32*65
#define ROWS3 3072         // 3*HID
#define N4BIG 17160        // INGRU/4 float4s per w_ih0 row
#define CHUNKS 8
#define CHLEN  2145        // N4BIG / CHUNKS (exact)
#define CHMAIN 2048        // 8 * 256
#define CHTAIL 97          // CHLEN - CHMAIN
#define MVBIG_GRID (ROWS3 * CHUNKS + ROWS3)   // 27648

typedef float f4 __attribute__((ext_vector_type(4)));

__device__ __forceinline__ float lrelu(float x) { return x > 0.f ? x : 0.2f * x; }
__device__ __forceinline__ float sigm(float x)  { return 1.f / (1.f + expf(-x)); }
__device__ __forceinline__ float dot4(f4 a, f4 b) {
    return a.x * b.x + a.y * b.y + a.z * b.z + a.w * b.w;
}

// block-wide reduce of acc -> dst. Uniform control flow required.
__device__ __forceinline__ void block_flush(float acc, float* dst, float* red,
                                            int tid, bool use_atomic) {
    for (int off = 32; off; off >>= 1) acc += __shfl_down(acc, off);
    if ((tid & 63) == 0) red[tid >> 6] = acc;
    __syncthreads();
    if (tid == 0) {
        const float t = red[0] + red[1] + red[2] + red[3];
        if (use_atomic) atomicAdd(dst, t);
        else            *dst = t;
    }
}

__device__ __forceinline__ float agent_load(const float* p) {
    return __hip_atomic_load(p, __ATOMIC_RELAXED, __HIP_MEMORY_SCOPE_AGENT);
}

// ---------------------------------------------------------------------------
// K1: blocks 0..32 build x_in (one per node); block 33 zeroes the atomic
// accumulators + ticket counters (re-zeroed every call: graph-replay safe);
// blocks 34.. compute gh0 = w_hh0 @ hidden[0] (independent of x_in).
// GAT algebra: hub input is 0 -> er[0]=0 (arf/art unused); z factorizes so
// the hub aggregate is a scalar per head.
// ---------------------------------------------------------------------------
__global__ void __launch_bounds__(256) prep_kernel(
    const float* __restrict__ data,
    const float* __restrict__ Wf, const float* __restrict__ alf,
    const float* __restrict__ bf,
    const float* __restrict__ Wt, const float* __restrict__ alt,
    const float* __restrict__ bt,
    float* __restrict__ x_in, float* __restrict__ gi0_zero,
    unsigned* __restrict__ ctrs,
    const float* __restrict__ w_hh0, const float* __restrict__ hidden0,
    float* __restrict__ gh0)
{
    const int n = blockIdx.x;
    const int tid = threadIdx.x;

    if (n >= NNODE + 1) {                   // gh0 row
        const int r = n - (NNODE + 1);
        __shared__ float red[4];
        const f4* A = (const f4*)w_hh0 + (size_t)r * 256;
        const f4 a = __builtin_nontemporal_load(&A[tid]);
        const f4 x = ((const f4*)hidden0)[tid];
        block_flush(dot4(a, x), gh0 + r, red, tid, false);
        return;
    }
    if (n == NNODE) {                       // zero atomic targets + tickets
        for (int i = tid; i < ROWS3; i += 256) gi0_zero[i] = 0.f;
        if (tid < 2) ctrs[tid] = 0u;
        return;
    }

    __shared__ float sS[32];                // feature-GAT hub scalar per head
    __shared__ float sSt[32];               // time-GAT hub scalar per feature

    if (n == 0) {
        if (tid < 32) {
            float Sa = 0.f;
            for (int o = 0; o < 32; ++o) Sa += Wf[tid * 32 + o] * alf[tid * 32 + o];
            float m = 0.f;                  // hub self-edge: e = lrelu(0) = 0
            for (int u = 1; u <= 32; ++u)
                m = fmaxf(m, lrelu(data[31 * 32 + u - 1] * Sa));
            float den = expf(-m), num = 0.f;
            for (int u = 1; u <= 32; ++u) {
                float x = data[31 * 32 + u - 1];
                float w = expf(lrelu(x * Sa) - m);
                den += w; num += w * x;
            }
            sS[tid] = num / den;
        } else if (tid < 64) {
            const int i = tid - 32;
            float ca = 0.f;
            for (int o = 0; o < 32; ++o) ca += Wt[o] * alt[o];
            float m = 0.f;
            for (int u = 1; u <= 32; ++u)
                m = fmaxf(m, lrelu(data[i * 32 + u - 1] * ca));
            float den = expf(-m), num = 0.f;
            for (int u = 1; u <= 32; ++u) {
                float y = data[i * 32 + u - 1];
                float w = expf(lrelu(y * ca) - m);
                den += w; num += w * y;
            }
            sSt[i] = num / den;
        }
        __syncthreads();
    }

    float* out = x_in + n * 2080;           // node slice is contiguous
    for (int q = tid; q < 2080; q += 256) {
        const int h = q / 65, c = q % 65;
        float v;
        if (c == 0) {
            v = (n == 0) ? 0.f : data[(n - 1) * 32 + h];
        } else if (c < 33) {
            const float vf = (n == 0) ? sS[h] : data[31 * 32 + (n - 1)];
            v = vf * Wf[h * 32 + (c - 1)] + bf[h * 32 + (c - 1)];
        } else {
            const float vt = (n == 0) ? sSt[h] : data[h * 32 + (n - 1)];
            v = vt * Wt[c - 33] + bt[c - 33];
        }
        out[q] = v;
    }
}

// ---------------------------------------------------------------------------
// K2: layer-0 big matvec (R4-proven sweep; X-loads issued BEFORE A-loads so
// each FMA unlocks on its own A arrival instead of vmcnt-waiting for all 8).
// bid = row*8 + chunk => consecutive blocks stream consecutive memory; one
// short-lived block per chunk keeps MLP high (R5's persistent variant
// regressed). Tail blocks compute gh1 = w_hh1 @ hidden[1].
// FUSED EPILOGUE: every block takes an ACQ_REL ticket after its flush (the
// release orders the gi0 atomicAdd before the ticket; the final acquire
// synchronizes with all prior releases). The last block runs gru_cell
// layer 0 inline, reading gi0 with agent-scope loads.
// ---------------------------------------------------------------------------
__global__ void __launch_bounds__(256) mv_big(
    const float* __restrict__ A0, const float* __restrict__ x0,
    float* __restrict__ y0,
    const float* __restrict__ A1, const float* __restrict__ x1,
    float* __restrict__ y1,
    unsigned* __restrict__ ctr,
    const float* __restrict__ gh0,
    const float* __restrict__ bih, const float* __restrict__ bhh,
    const float* __restrict__ hprev,
    float* __restrict__ h0, float* __restrict__ h0_out)
{
    const int tid = threadIdx.x;
    float acc = 0.f;
    float* dst;
    bool is_big;
    __shared__ float red[4];

    if (blockIdx.x < ROWS3 * CHUNKS) {
        is_big = true;
        const int row = blockIdx.x >> 3, c = blockIdx.x & 7;
        const f4* A = (const f4*)A0 + (size_t)row * N4BIG + c * CHLEN;
        const f4* X = (const f4*)x0 + c * CHLEN;

        f4 a[8], x[8];
#pragma unroll
        for (int i = 0; i < 8; ++i)
            x[i] = X[tid + i * 256];
#pragma unroll
        for (int i = 0; i < 8; ++i)
            a[i] = __builtin_nontemporal_load(&A[tid + i * 256]);
        float acc2 = 0.f;
#pragma unroll
        for (int i = 0; i < 8; i += 2) {
            acc  += dot4(a[i],     x[i]);
            acc2 += dot4(a[i + 1], x[i + 1]);
        }
        if (tid < CHTAIL) {
            const f4 xt = X[CHMAIN + tid];
            const f4 at = __builtin_nontemporal_load(&A[CHMAIN + tid]);
            acc2 += dot4(at, xt);
        }
        acc += acc2;
        dst = y0 + row;
    } else {
        is_big = false;
        const int r = blockIdx.x - ROWS3 * CHUNKS;
        const f4* A = (const f4*)A1 + (size_t)r * 256;
        const f4 a = __builtin_nontemporal_load(&A[tid]);
        const f4 x = ((const f4*)x1)[tid];
        acc = dot4(a, x);
        dst = y1 + r;
    }

    block_flush(acc, dst, red, tid, is_big);

    // ---- fused gru0 epilogue (last-ticket block only) ----
    __shared__ int last;
    if (tid == 0) {
        const unsigned t = __hip_atomic_fetch_add(ctr, 1u, __ATOMIC_ACQ_REL,
                                                  __HIP_MEMORY_SCOPE_AGENT);
        last = (t == MVBIG_GRID - 1);
    }
    __syncthreads();
    if (last) {
        for (int j = tid; j < HID; j += 256) {
            const float ir = agent_load(y0 + j)           + bih[j];
            const float iz = agent_load(y0 + HID + j)     + bih[HID + j];
            const float in_ = agent_load(y0 + 2 * HID + j) + bih[2 * HID + j];
            const float r  = sigm(ir + gh0[j] + bhh[j]);
            const float zg = sigm(iz + gh0[HID + j] + bhh[HID + j]);
            const float nn = tanhf(in_ + r * (gh0[2 * HID + j] + bhh[2 * HID + j]));
            const float h  = (1.f - zg) * nn + zg * hprev[j];
            h0[j] = h;
            h0_out[j] = h;
        }
    }
}

// ---------------------------------------------------------------------------
// K3: gi1 = w_ih1 @ h0 (3072 blocks) + fused gru1 epilogue in the
// last-ticket block (gh1 was produced by K2 — prior kernel, visible).
// ---------------------------------------------------------------------------
__global__ void __launch_bounds__(256) mv_small(
    const float* __restrict__ A0, const float* __restrict__ x0,
    float* __restrict__ y0,
    unsigned* __restrict__ ctr,
    const float* __restrict__ gh1,
    const float* __restrict__ bih, const float* __restrict__ bhh,
    const float* __restrict__ hprev,
    float* __restrict__ out1, float* __restrict__ out2)
{
    const int tid = threadIdx.x;
    __shared__ float red[4];
    const f4* A = (const f4*)A0 + (size_t)blockIdx.x * 256;
    const f4 a = __builtin_nontemporal_load(&A[tid]);
    const f4 x = ((const f4*)x0)[tid];
    block_flush(dot4(a, x), y0 + blockIdx.x, red, tid, false);

    __shared__ int last;
    if (tid == 0) {
        const unsigned t = __hip_atomic_fetch_add(ctr, 1u, __ATOMIC_ACQ_REL,
                                                  __HIP_MEMORY_SCOPE_AGENT);
        last = (t == ROWS3 - 1);
    }
    __syncthreads();
    if (last) {
        for (int j = tid; j < HID; j += 256) {
            const float ir = agent_load(y0 + j)           + bih[j];
            const float iz = agent_load(y0 + HID + j)     + bih[HID + j];
            const float in_ = agent_load(y0 + 2 * HID + j) + bih[2 * HID + j];
            const float r  = sigm(ir + gh1[j] + bhh[j]);
            const float zg = sigm(iz + gh1[HID + j] + bhh[HID + j]);
            const float nn = tanhf(in_ + r * (gh1[2 * HID + j] + bhh[2 * HID + j]));
            const float h  = (1.f - zg) * nn + zg * hprev[j];
            out1[j] = h;
            out2[j] = h;
        }
    }
}

extern "C" void kernel_launch(void* const* d_in, const int* in_sizes, int n_in,
                              void* d_out, int out_size, void* d_ws, size_t ws_size,
                              hipStream_t stream)
{
    const float* data   = (const float*)d_in[0];
    const float* hidden = (const float*)d_in[1];
    const float* Wf     = (const float*)d_in[2];
    const float* alf    = (const float*)d_in[3];
    // d_in[4] = arf: provably unused (hub input is 0 -> er[0] == 0)
    const float* bf     = (const float*)d_in[5];
    const float* Wt     = (const float*)d_in[6];
    const float* alt    = (const float*)d_in[7];
    // d_in[8] = art: unused
    const float* bt     = (const float*)d_in[9];
    const float* w_ih0  = (const float*)d_in[10];
    const float* w_hh0  = (const float*)d_in[11];
    const float* b_ih0  = (const float*)d_in[12];
    const float* b_hh0  = (const float*)d_in[13];
    const float* w_ih1  = (const float*)d_in[14];
    const float* w_hh1  = (const float*)d_in[15];
    const float* b_ih1  = (const float*)d_in[16];
    const float* b_hh1  = (const float*)d_in[17];

    float* out  = (float*)d_out;       // [h1 (1024) | h0 (1024) | h1 (1024)]
    float* ws   = (float*)d_ws;
    float* x_in = ws;                  // 68640
    float* gi0  = ws + INGRU;          // 3072 (atomic accumulator, zeroed in prep)
    float* gh0  = gi0 + ROWS3;         // 3072
    float* h0   = gh0 + ROWS3;         // 1024
    float* gi1  = h0 + HID;            // 3072
    float* gh1  = gi1 + ROWS3;         // 3072
    unsigned* ctrs = (unsigned*)(gh1 + ROWS3);   // 2 ticket counters

    // K1: x_in + zero(gi0, tickets) + gh0 (independent of x_in)
    prep_kernel<<<NNODE + 1 + ROWS3, 256, 0, stream>>>(
        data, Wf, alf, bf, Wt, alt, bt, x_in, gi0, ctrs, w_hh0, hidden, gh0);

    // K2: gi0 (843 MB sweep) + gh1 tail + fused gru0 epilogue -> h0
    mv_big<<<MVBIG_GRID, 256, 0, stream>>>(
        w_ih0, x_in, gi0,
        w_hh1, hidden + HID, gh1,
        ctrs, gh0, b_ih0, b_hh0, hidden,
        h0, out + HID);

    // K3: gi1 = w_ih1 @ h0 + fused gru1 epilogue -> out
    mv_small<<<ROWS3, 256, 0, stream>>>(
        w_ih1, h0, gi1,
        ctrs + 1, gh1, b_ih1, b_hh1, hidden + HID,
        out, out + 2 * HID);
}

// Round 8
// 172.149 us; speedup vs baseline: 9.1480x; 9.1480x over previous
//
#include <hip/hip_runtime.h>
#include <math.h>

#define FEATS 32
#define NNODE 33
#define HID   1024
#define INGRU 68640        // 33*32*65
#define ROWS3 3072         // 3*HID
#define N4BIG 17160        // INGRU/4 float4s per w_ih0 row
#define CHUNKS 8
#define CHLEN  2145        // N4BIG / CHUNKS (exact)
#define CHMAIN 2048        // 8 * 256
#define CHTAIL 97          // CHLEN - CHMAIN
#define GBIG   (ROWS3 * CHUNKS)   // 24576 big chunks
#define GPX    (GBIG / 8)         // 3072 chunks per XCD window

typedef float f4 __attribute__((ext_vector_type(4)));

__device__ __forceinline__ float lrelu(float x) { return x > 0.f ? x : 0.2f * x; }
__device__ __forceinline__ float sigm(float x)  { return 1.f / (1.f + expf(-x)); }
__device__ __forceinline__ float dot4(f4 a, f4 b) {
    return a.x * b.x + a.y * b.y + a.z * b.z + a.w * b.w;
}

// block-wide reduce of acc -> dst. Uniform control flow required.
__device__ __forceinline__ void block_flush(float acc, float* dst, float* red,
                                            int tid, bool use_atomic) {
    for (int off = 32; off; off >>= 1) acc += __shfl_down(acc, off);
    if ((tid & 63) == 0) red[tid >> 6] = acc;
    __syncthreads();
    if (tid == 0) {
        const float t = red[0] + red[1] + red[2] + red[3];
        if (use_atomic) atomicAdd(dst, t);
        else            *dst = t;
    }
}

// ---------------------------------------------------------------------------
// K1: blocks 0..32 build x_in (one per node); block 33 zeroes gi0 (atomic
// target, re-zeroed every call for graph-replay determinism); blocks
// 34..3105 compute gh0 = w_hh0 @ hidden[0] (independent of x_in — uses CUs
// that would otherwise idle during prep).
// GAT algebra: hub input is 0 -> er[0]=0 (arf/art unused); z factorizes so
// the hub aggregate is a scalar per head.
// ---------------------------------------------------------------------------
__global__ void __launch_bounds__(256) prep_kernel(
    const float* __restrict__ data,
    const float* __restrict__ Wf, const float* __restrict__ alf,
    const float* __restrict__ bf,
    const float* __restrict__ Wt, const float* __restrict__ alt,
    const float* __restrict__ bt,
    float* __restrict__ x_in, float* __restrict__ gi0_zero,
    const float* __restrict__ w_hh0, const float* __restrict__ hidden0,
    float* __restrict__ gh0)
{
    const int n = blockIdx.x;
    const int tid = threadIdx.x;

    if (n >= NNODE + 1) {                   // gh0 row
        const int r = n - (NNODE + 1);
        __shared__ float red[4];
        const f4* A = (const f4*)w_hh0 + (size_t)r * 256;
        const f4 a = __builtin_nontemporal_load(&A[tid]);
        const f4 x = ((const f4*)hidden0)[tid];
        block_flush(dot4(a, x), gh0 + r, red, tid, false);
        return;
    }
    if (n == NNODE) {                       // zero the atomic target
        for (int i = tid; i < ROWS3; i += 256) gi0_zero[i] = 0.f;
        return;
    }

    __shared__ float sS[32];                // feature-GAT hub scalar per head
    __shared__ float sSt[32];               // time-GAT hub scalar per feature

    if (n == 0) {
        if (tid < 32) {
            float Sa = 0.f;
            for (int o = 0; o < 32; ++o) Sa += Wf[tid * 32 + o] * alf[tid * 32 + o];
            float m = 0.f;                  // hub self-edge: e = lrelu(0) = 0
            for (int u = 1; u <= 32; ++u)
                m = fmaxf(m, lrelu(data[31 * 32 + u - 1] * Sa));
            float den = expf(-m), num = 0.f;
            for (int u = 1; u <= 32; ++u) {
                float x = data[31 * 32 + u - 1];
                float w = expf(lrelu(x * Sa) - m);
                den += w; num += w * x;
            }
            sS[tid] = num / den;
        } else if (tid < 64) {
            const int i = tid - 32;
            float ca = 0.f;
            for (int o = 0; o < 32; ++o) ca += Wt[o] * alt[o];
            float m = 0.f;
            for (int u = 1; u <= 32; ++u)
                m = fmaxf(m, lrelu(data[i * 32 + u - 1] * ca));
            float den = expf(-m), num = 0.f;
            for (int u = 1; u <= 32; ++u) {
                float y = data[i * 32 + u - 1];
                float w = expf(lrelu(y * ca) - m);
                den += w; num += w * y;
            }
            sSt[i] = num / den;
        }
        __syncthreads();
    }

    float* out = x_in + n * 2080;           // node slice is contiguous
    for (int q = tid; q < 2080; q += 256) {
        const int h = q / 65, c = q % 65;
        float v;
        if (c == 0) {
            v = (n == 0) ? 0.f : data[(n - 1) * 32 + h];
        } else if (c < 33) {
            const float vf = (n == 0) ? sS[h] : data[31 * 32 + (n - 1)];
            v = vf * Wf[h * 32 + (c - 1)] + bf[h * 32 + (c - 1)];
        } else {
            const float vt = (n == 0) ? sSt[h] : data[h * 32 + (n - 1)];
            v = vt * Wt[c - 33] + bt[c - 33];
        }
        out[q] = v;
    }
}

// ---------------------------------------------------------------------------
// K2: layer-0 big matvec (R4-proven sweep; NO device-sync in here — R7's
// ACQ_REL ticket epilogue collapsed BW 5.7 TB/s -> 0.3 TB/s via per-XCD L2
// invalidates). XCD-CONTIGUOUS remap: blockIdx round-robins XCDs (bid%8),
// so g = (bid&7)*GPX + bid>>3 gives each XCD one dense, monotonically
// advancing 105 MB window over w_ih0 (per-L2 sequential stream) instead of
// an 8-way interleave. Chunk g -> row g>>3, x-chunk g&7. A-loads
// nontemporal; 8 x 256 f4 pairs + 97 tail; one atomicAdd per chunk.
// Tail blocks compute gh1 = w_hh1 @ hidden[1] (independent of h0).
// ---------------------------------------------------------------------------
__global__ void __launch_bounds__(256) mv_big(
    const float* __restrict__ A0, const float* __restrict__ x0,
    float* __restrict__ y0,
    const float* __restrict__ A1, const float* __restrict__ x1,
    float* __restrict__ y1)
{
    const int tid = threadIdx.x;
    float acc = 0.f;
    float* dst;
    bool is_big;
    __shared__ float red[4];

    if (blockIdx.x < GBIG) {
        is_big = true;
        const int g = (blockIdx.x & 7) * GPX + (blockIdx.x >> 3);
        const int row = g >> 3, c = g & 7;
        const f4* A = (const f4*)A0 + (size_t)row * N4BIG + c * CHLEN;
        const f4* X = (const f4*)x0 + c * CHLEN;

        f4 a[8], x[8];
#pragma unroll
        for (int i = 0; i < 8; ++i)
            x[i] = X[tid + i * 256];
#pragma unroll
        for (int i = 0; i < 8; ++i)
            a[i] = __builtin_nontemporal_load(&A[tid + i * 256]);
        float acc2 = 0.f;
#pragma unroll
        for (int i = 0; i < 8; i += 2) {
            acc  += dot4(a[i],     x[i]);
            acc2 += dot4(a[i + 1], x[i + 1]);
        }
        if (tid < CHTAIL) {
            const f4 xt = X[CHMAIN + tid];
            const f4 at = __builtin_nontemporal_load(&A[CHMAIN + tid]);
            acc2 += dot4(at, xt);
        }
        acc += acc2;
        dst = y0 + row;
    } else {
        is_big = false;
        const int r = blockIdx.x - GBIG;
        const f4* A = (const f4*)A1 + (size_t)r * 256;
        const f4 a = __builtin_nontemporal_load(&A[tid]);
        const f4 x = ((const f4*)x1)[tid];
        acc = dot4(a, x);
        dst = y1 + r;
    }

    block_flush(acc, dst, red, tid, is_big);
}

// ---------------------------------------------------------------------------
// K4: gi1 = w_ih1 @ h0 only (gh1 done in mv_big's tail). 3072 blocks.
// ---------------------------------------------------------------------------
__global__ void __launch_bounds__(256) mv_small(
    const float* __restrict__ A0, const float* __restrict__ x0,
    float* __restrict__ y0)
{
    const int tid = threadIdx.x;
    __shared__ float red[4];
    const f4* A = (const f4*)A0 + (size_t)blockIdx.x * 256;
    const f4 a = __builtin_nontemporal_load(&A[tid]);
    const f4 x = ((const f4*)x0)[tid];
    block_flush(dot4(a, x), y0 + blockIdx.x, red, tid, false);
}

// ---------------------------------------------------------------------------
// K3/K5: GRU pointwise cell with biases folded in (gi/gh are raw dots).
// ---------------------------------------------------------------------------
__global__ void __launch_bounds__(256) gru_cell(
    const float* __restrict__ gi, const float* __restrict__ gh,
    const float* __restrict__ bih, const float* __restrict__ bhh,
    const float* __restrict__ hprev,
    float* __restrict__ hout, float* __restrict__ hout2, float* __restrict__ hout3)
{
    const int j = blockIdx.x * blockDim.x + threadIdx.x;
    const float r  = sigm(gi[j] + bih[j] + gh[j] + bhh[j]);
    const float zg = sigm(gi[HID + j] + bih[HID + j] + gh[HID + j] + bhh[HID + j]);
    const float n  = tanhf(gi[2 * HID + j] + bih[2 * HID + j]
                           + r * (gh[2 * HID + j] + bhh[2 * HID + j]));
    const float h  = (1.f - zg) * n + zg * hprev[j];
    hout[j] = h;
    if (hout2) hout2[j] = h;
    if (hout3) hout3[j] = h;
}

extern "C" void kernel_launch(void* const* d_in, const int* in_sizes, int n_in,
                              void* d_out, int out_size, void* d_ws, size_t ws_size,
                              hipStream_t stream)
{
    const float* data   = (const float*)d_in[0];
    const float* hidden = (const float*)d_in[1];
    const float* Wf     = (const float*)d_in[2];
    const float* alf    = (const float*)d_in[3];
    // d_in[4] = arf: provably unused (hub input is 0 -> er[0] == 0)
    const float* bf     = (const float*)d_in[5];
    const float* Wt     = (const float*)d_in[6];
    const float* alt    = (const float*)d_in[7];
    // d_in[8] = art: unused
    const float* bt     = (const float*)d_in[9];
    const float* w_ih0  = (const float*)d_in[10];
    const float* w_hh0  = (const float*)d_in[11];
    const float* b_ih0  = (const float*)d_in[12];
    const float* b_hh0  = (const float*)d_in[13];
    const float* w_ih1  = (const float*)d_in[14];
    const float* w_hh1  = (const float*)d_in[15];
    const float* b_ih1  = (const float*)d_in[16];
    const float* b_hh1  = (const float*)d_in[17];

    float* out  = (float*)d_out;       // [h1 (1024) | h0 (1024) | h1 (1024)]
    float* ws   = (float*)d_ws;
    float* x_in = ws;                  // 68640
    float* gi0  = ws + INGRU;          // 3072 (atomic accumulator, zeroed in prep)
    float* gh0  = gi0 + ROWS3;         // 3072
    float* h0   = gh0 + ROWS3;         // 1024
    float* gi1  = h0 + HID;            // 3072
    float* gh1  = gi1 + ROWS3;         // 3072

    // K1: x_in + zero(gi0) + gh0 (independent of x_in)
    prep_kernel<<<NNODE + 1 + ROWS3, 256, 0, stream>>>(
        data, Wf, alf, bf, Wt, alt, bt, x_in, gi0, w_hh0, hidden, gh0);

    // K2: gi0 (843 MB sweep, XCD-contiguous) + gh1 tail
    mv_big<<<GBIG + ROWS3, 256, 0, stream>>>(
        w_ih0, x_in, gi0,
        w_hh1, hidden + HID, gh1);

    gru_cell<<<4, 256, 0, stream>>>(gi0, gh0, b_ih0, b_hh0, hidden,
                                    h0, out + HID, nullptr);

    // K4: gi1 = w_ih1 @ h0
    mv_small<<<ROWS3, 256, 0, stream>>>(w_ih1, h0, gi1);

    gru_cell<<<4, 256, 0, stream>>>(gi1, gh1, b_ih1, b_hh1, hidden + HID,
                                    out, out + 2 * HID, nullptr);
}

// Round 9
// 169.110 us; speedup vs baseline: 9.3124x; 1.0180x over previous
//
#include <hip/hip_runtime.h>
#include <math.h>

#define FEATS 32
#define NNODE 33
#define HID   1024
#define INGRU 68640        // 33*32*65
#define ROWS3 3072         // 3*HID
#define N4BIG 17160        // INGRU/4 float4s per w_ih0 row
#define CHUNKS 4
#define CHLEN  4290        // N4BIG / CHUNKS (exact)
#define CHMAIN 4096        // 16 * 256
#define CHTAIL 194         // CHLEN - CHMAIN
#define GBIG   (ROWS3 * CHUNKS)   // 12288 big chunks

typedef float f4 __attribute__((ext_vector_type(4)));

__device__ __forceinline__ float lrelu(float x) { return x > 0.f ? x : 0.2f * x; }
__device__ __forceinline__ float sigm(float x)  { return 1.f / (1.f + expf(-x)); }
__device__ __forceinline__ float dot4(f4 a, f4 b) {
    return a.x * b.x + a.y * b.y + a.z * b.z + a.w * b.w;
}

// block-wide reduce of acc -> dst. Uniform control flow required.
__device__ __forceinline__ void block_flush(float acc, float* dst, float* red,
                                            int tid, bool use_atomic) {
    for (int off = 32; off; off >>= 1) acc += __shfl_down(acc, off);
    if ((tid & 63) == 0) red[tid >> 6] = acc;
    __syncthreads();
    if (tid == 0) {
        const float t = red[0] + red[1] + red[2] + red[3];
        if (use_atomic) atomicAdd(dst, t);
        else            *dst = t;
    }
}

// ---------------------------------------------------------------------------
// K1: blocks 0..32 build x_in (one per node); block 33 zeroes gi0 (atomic
// target, re-zeroed every call for graph-replay determinism); blocks
// 34..3105 compute gh0 = w_hh0 @ hidden[0] (independent of x_in — uses CUs
// that would otherwise idle during prep).
// GAT algebra: hub input is 0 -> er[0]=0 (arf/art unused); z factorizes so
// the hub aggregate is a scalar per head.
// ---------------------------------------------------------------------------
__global__ void __launch_bounds__(256) prep_kernel(
    const float* __restrict__ data,
    const float* __restrict__ Wf, const float* __restrict__ alf,
    const float* __restrict__ bf,
    const float* __restrict__ Wt, const float* __restrict__ alt,
    const float* __restrict__ bt,
    float* __restrict__ x_in, float* __restrict__ gi0_zero,
    const float* __restrict__ w_hh0, const float* __restrict__ hidden0,
    float* __restrict__ gh0)
{
    const int n = blockIdx.x;
    const int tid = threadIdx.x;

    if (n >= NNODE + 1) {                   // gh0 row
        const int r = n - (NNODE + 1);
        __shared__ float red[4];
        const f4* A = (const f4*)w_hh0 + (size_t)r * 256;
        const f4 a = __builtin_nontemporal_load(&A[tid]);
        const f4 x = ((const f4*)hidden0)[tid];
        block_flush(dot4(a, x), gh0 + r, red, tid, false);
        return;
    }
    if (n == NNODE) {                       // zero the atomic target
        for (int i = tid; i < ROWS3; i += 256) gi0_zero[i] = 0.f;
        return;
    }

    __shared__ float sS[32];                // feature-GAT hub scalar per head
    __shared__ float sSt[32];               // time-GAT hub scalar per feature

    if (n == 0) {
        if (tid < 32) {
            float Sa = 0.f;
            for (int o = 0; o < 32; ++o) Sa += Wf[tid * 32 + o] * alf[tid * 32 + o];
            float m = 0.f;                  // hub self-edge: e = lrelu(0) = 0
            for (int u = 1; u <= 32; ++u)
                m = fmaxf(m, lrelu(data[31 * 32 + u - 1] * Sa));
            float den = expf(-m), num = 0.f;
            for (int u = 1; u <= 32; ++u) {
                float x = data[31 * 32 + u - 1];
                float w = expf(lrelu(x * Sa) - m);
                den += w; num += w * x;
            }
            sS[tid] = num / den;
        } else if (tid < 64) {
            const int i = tid - 32;
            float ca = 0.f;
            for (int o = 0; o < 32; ++o) ca += Wt[o] * alt[o];
            float m = 0.f;
            for (int u = 1; u <= 32; ++u)
                m = fmaxf(m, lrelu(data[i * 32 + u - 1] * ca));
            float den = expf(-m), num = 0.f;
            for (int u = 1; u <= 32; ++u) {
                float y = data[i * 32 + u - 1];
                float w = expf(lrelu(y * ca) - m);
                den += w; num += w * y;
            }
            sSt[i] = num / den;
        }
        __syncthreads();
    }

    float* out = x_in + n * 2080;           // node slice is contiguous
    for (int q = tid; q < 2080; q += 256) {
        const int h = q / 65, c = q % 65;
        float v;
        if (c == 0) {
            v = (n == 0) ? 0.f : data[(n - 1) * 32 + h];
        } else if (c < 33) {
            const float vf = (n == 0) ? sS[h] : data[31 * 32 + (n - 1)];
            v = vf * Wf[h * 32 + (c - 1)] + bf[h * 32 + (c - 1)];
        } else {
            const float vt = (n == 0) ? sSt[h] : data[h * 32 + (n - 1)];
            v = vt * Wt[c - 33] + bt[c - 33];
        }
        out[q] = v;
    }
}

// ---------------------------------------------------------------------------
// K2: layer-0 big matvec. CHUNKS=4 depth experiment: bid = row*4 + chunk,
// natural block order (R8's XCD remap was neutral-negative; reverted);
// each block owns ONE contiguous 68 KB stream with 16 A-loads + 16 X-loads
// in flight per thread, NO mid-block barriers (R5's regression isolated to
// its barrier-flushes), single atomicAdd per block (half of CHUNKS=8).
// NO device-scope sync in here — R7's ACQ_REL tickets collapsed BW
// 5.7 -> 0.3 TB/s. Tail blocks compute gh1 = w_hh1 @ hidden[1].
// ---------------------------------------------------------------------------
__global__ void __launch_bounds__(256) mv_big(
    const float* __restrict__ A0, const float* __restrict__ x0,
    float* __restrict__ y0,
    const float* __restrict__ A1, const float* __restrict__ x1,
    float* __restrict__ y1)
{
    const int tid = threadIdx.x;
    float acc = 0.f;
    float* dst;
    bool is_big;
    __shared__ float red[4];

    if (blockIdx.x < GBIG) {
        is_big = true;
        const int row = blockIdx.x >> 2, c = blockIdx.x & 3;
        const f4* A = (const f4*)A0 + (size_t)row * N4BIG + c * CHLEN;
        const f4* X = (const f4*)x0 + c * CHLEN;

        f4 a[16], x[16];
#pragma unroll
        for (int i = 0; i < 16; ++i)
            x[i] = X[tid + i * 256];
#pragma unroll
        for (int i = 0; i < 16; ++i)
            a[i] = __builtin_nontemporal_load(&A[tid + i * 256]);
        float s0 = 0.f, s1 = 0.f, s2 = 0.f, s3 = 0.f;
#pragma unroll
        for (int i = 0; i < 16; i += 4) {
            s0 += dot4(a[i],     x[i]);
            s1 += dot4(a[i + 1], x[i + 1]);
            s2 += dot4(a[i + 2], x[i + 2]);
            s3 += dot4(a[i + 3], x[i + 3]);
        }
        if (tid < CHTAIL) {
            const f4 xt = X[CHMAIN + tid];
            const f4 at = __builtin_nontemporal_load(&A[CHMAIN + tid]);
            s0 += dot4(at, xt);
        }
        acc = (s0 + s1) + (s2 + s3);
        dst = y0 + row;
    } else {
        is_big = false;
        const int r = blockIdx.x - GBIG;
        const f4* A = (const f4*)A1 + (size_t)r * 256;
        const f4 a = __builtin_nontemporal_load(&A[tid]);
        const f4 x = ((const f4*)x1)[tid];
        acc = dot4(a, x);
        dst = y1 + r;
    }

    block_flush(acc, dst, red, tid, is_big);
}

// ---------------------------------------------------------------------------
// K4: gi1 = w_ih1 @ h0 only (gh1 done in mv_big's tail). 3072 blocks.
// ---------------------------------------------------------------------------
__global__ void __launch_bounds__(256) mv_small(
    const float* __restrict__ A0, const float* __restrict__ x0,
    float* __restrict__ y0)
{
    const int tid = threadIdx.x;
    __shared__ float red[4];
    const f4* A = (const f4*)A0 + (size_t)blockIdx.x * 256;
    const f4 a = __builtin_nontemporal_load(&A[tid]);
    const f4 x = ((const f4*)x0)[tid];
    block_flush(dot4(a, x), y0 + blockIdx.x, red, tid, false);
}

// ---------------------------------------------------------------------------
// K3/K5: GRU pointwise cell with biases folded in (gi/gh are raw dots).
// ---------------------------------------------------------------------------
__global__ void __launch_bounds__(256) gru_cell(
    const float* __restrict__ gi, const float* __restrict__ gh,
    const float* __restrict__ bih, const float* __restrict__ bhh,
    const float* __restrict__ hprev,
    float* __restrict__ hout, float* __restrict__ hout2, float* __restrict__ hout3)
{
    const int j = blockIdx.x * blockDim.x + threadIdx.x;
    const float r  = sigm(gi[j] + bih[j] + gh[j] + bhh[j]);
    const float zg = sigm(gi[HID + j] + bih[HID + j] + gh[HID + j] + bhh[HID + j]);
    const float n  = tanhf(gi[2 * HID + j] + bih[2 * HID + j]
                           + r * (gh[2 * HID + j] + bhh[2 * HID + j]));
    const float h  = (1.f - zg) * n + zg * hprev[j];
    hout[j] = h;
    if (hout2) hout2[j] = h;
    if (hout3) hout3[j] = h;
}

extern "C" void kernel_launch(void* const* d_in, const int* in_sizes, int n_in,
                              void* d_out, int out_size, void* d_ws, size_t ws_size,
                              hipStream_t stream)
{
    const float* data   = (const float*)d_in[0];
    const float* hidden = (const float*)d_in[1];
    const float* Wf     = (const float*)d_in[2];
    const float* alf    = (const float*)d_in[3];
    // d_in[4] = arf: provably unused (hub input is 0 -> er[0] == 0)
    const float* bf     = (const float*)d_in[5];
    const float* Wt     = (const float*)d_in[6];
    const float* alt    = (const float*)d_in[7];
    // d_in[8] = art: unused
    const float* bt     = (const float*)d_in[9];
    const float* w_ih0  = (const float*)d_in[10];
    const float* w_hh0  = (const float*)d_in[11];
    const float* b_ih0  = (const float*)d_in[12];
    const float* b_hh0  = (const float*)d_in[13];
    const float* w_ih1  = (const float*)d_in[14];
    const float* w_hh1  = (const float*)d_in[15];
    const float* b_ih1  = (const float*)d_in[16];
    const float* b_hh1  = (const float*)d_in[17];

    float* out  = (float*)d_out;       // [h1 (1024) | h0 (1024) | h1 (1024)]
    float* ws   = (float*)d_ws;
    float* x_in = ws;                  // 68640
    float* gi0  = ws + INGRU;          // 3072 (atomic accumulator, zeroed in prep)
    float* gh0  = gi0 + ROWS3;         // 3072
    float* h0   = gh0 + ROWS3;         // 1024
    float* gi1  = h0 + HID;            // 3072
    float* gh1  = gi1 + ROWS3;         // 3072

    // K1: x_in + zero(gi0) + gh0 (independent of x_in)
    prep_kernel<<<NNODE + 1 + ROWS3, 256, 0, stream>>>(
        data, Wf, alf, bf, Wt, alt, bt, x_in, gi0, w_hh0, hidden, gh0);

    // K2: gi0 (843 MB sweep, CHUNKS=4 deep streams) + gh1 tail
    mv_big<<<GBIG + ROWS3, 256, 0, stream>>>(
        w_ih0, x_in, gi0,
        w_hh1, hidden + HID, gh1);

    gru_cell<<<4, 256, 0, stream>>>(gi0, gh0, b_ih0, b_hh0, hidden,
                                    h0, out + HID, nullptr);

    // K4: gi1 = w_ih1 @ h0
    mv_small<<<ROWS3, 256, 0, stream>>>(w_ih1, h0, gi1);

    gru_cell<<<4, 256, 0, stream>>>(gi1, gh1, b_ih1, b_hh1, hidden + HID,
                                    out, out + 2 * HID, nullptr);
}